// Round 4
// baseline (317.187 us; speedup 1.0000x reference)
//
#include <hip/hip_runtime.h>

// RBFolution: out[b,y,x,f] = exp(-beta[f] * (||patch||^2 - 2 patch.ccs[:,f] + ||ccs[:,f]||^2))
// x: [32,112,112,32] f32, ccs: [288,128] f32, beta: [128] f32, out: [32,110,110,128] f32
//
// bf16 MFMA implicit GEMM; p_sq/c_sq fp32-exact (only cross term bf16, err ~1e-5).
// R8: occupancy attack, properly isolated (R5 bundled this with a VGPR=64 strangle).
// R5 counters showed every pipe idle (Mfma 7.6%, VALU 11%, HBM 39%, occupancy 31%):
// latency/phase-serialization bound at 3 blocks/CU. This round: ORPB=2/SROWS=4 ->
// LDS 31.9KB, __launch_bounds__(256,4) -> VGPR<=128 (acc=56 + ~50 working fits) ->
// 4 blocks/CU, 16 waves (+33% TLP), 1760 finer blocks stagger phases.
// Cost: fetch 77->103MB (+4us). nt stores kept (write-once output, no RFO).
// Stage loop = 14*256 float4 exactly, no tail, no row clamp (y0+3 <= 111 always).

typedef __attribute__((ext_vector_type(8))) short bf16x8;
typedef __attribute__((ext_vector_type(4))) float f32x4;

#define HH 112
#define WW 112
#define CC 32
#define HO 110
#define WO 110
#define NF 128
#define KD 288
#define RPX 114        // pixels per staged row in LDS (reads reach px 113)
#define XP 32          // bf16 elems per pixel (64 B): b128 frag reads spread uniformly over banks
#define ORPB 2         // output rows per block
#define SROWS 4        // staged input rows per block

__device__ __forceinline__ unsigned short f32_to_bf16(float f) {
    unsigned u = __float_as_uint(f);
    unsigned r = u + 0x7FFFu + ((u >> 16) & 1u);   // round-to-nearest-even
    return (unsigned short)(r >> 16);
}

// --- Prologue: ccs [288][128] f32 -> ccs_t [128][288] bf16 (all blocks);
//     block 0 threads 0..127 also compute c_sq[f] = sum_d ccs[d][f]^2 (coalesced column walk).
__global__ __launch_bounds__(256) void rbf_prologue(const float* __restrict__ ccs,
                                                    unsigned short* __restrict__ ccs_t,
                                                    float* __restrict__ c_sq) {
    int idx = blockIdx.x * 256 + threadIdx.x;     // 0..36863, coalesced read
    int d = idx >> 7;
    int f = idx & 127;
    ccs_t[f * KD + d] = f32_to_bf16(ccs[idx]);
    if (blockIdx.x == 0 && threadIdx.x < 128) {
        const int fc = threadIdx.x;
        float s = 0.f;
        #pragma unroll 8
        for (int dd = 0; dd < KD; ++dd) {
            float v = ccs[dd * NF + fc];
            s += v * v;
        }
        c_sq[fc] = s;
    }
}

// --- Main: one block per (2-row strip, b). 2 output rows, 4 staged input rows.
__global__ __launch_bounds__(256, 4) void rbf_main(const float* __restrict__ x,
                                                   const unsigned short* __restrict__ ccs_t,
                                                   const float* __restrict__ c_sq,
                                                   const float* __restrict__ beta,
                                                   float* __restrict__ out) {
    __shared__ unsigned short xs[SROWS * RPX * XP];   // 29184 B
    __shared__ float colsum[452];                     // 4 rows x 112 (stride 112) + overrun pad
    __shared__ float p_sq[ORPB * 112];                // 896 B   -> 31.9 KB total

    const int t = threadIdx.x;
    const int y0 = blockIdx.x * ORPB;  // 0,2,...,108
    const int b = blockIdx.y;          // 0..31

    // Stage x[y0..y0+3][0..111][0..31] -> LDS bf16; colsum from fp32 (exact p_sq).
    // 3584 float4 units = 14 * 256 exactly (no tail). y0+3 <= 111 always (no clamp).
    #pragma unroll
    for (int p = 0; p < 14; ++p) {
        int idx = t + p * 256;
        int q = idx & 7;              // channel quarter (4 floats)
        int ic = idx >> 3;            // 0..447 = i*112 + col
        int col = ic % 112;
        int i = ic / 112;
        const float4 v = *(const float4*)(x + ((size_t)(b * HH + y0 + i) * WW + col) * CC + q * 4);
        unsigned short h0 = f32_to_bf16(v.x), h1 = f32_to_bf16(v.y);
        unsigned short h2 = f32_to_bf16(v.z), h3 = f32_to_bf16(v.w);
        uint2 pk;
        pk.x = (unsigned)h0 | ((unsigned)h1 << 16);
        pk.y = (unsigned)h2 | ((unsigned)h3 << 16);
        *(uint2*)(&xs[(i * RPX + col) * XP + q * 4]) = pk;   // 8B, contiguous per wave
        float part = v.x * v.x + v.y * v.y + v.z * v.z + v.w * v.w;
        part += __shfl_xor(part, 1);
        part += __shfl_xor(part, 2);
        part += __shfl_xor(part, 4);
        if (q == 0) colsum[ic] = part;   // stride 112
    }
    __syncthreads();

    if (t < ORPB * 112) {   // 224 threads
        int r = t / 112;
        int c = t - r * 112;
        float s = 0.f;
        #pragma unroll
        for (int i = 0; i < 3; ++i)
            #pragma unroll
            for (int j = 0; j < 3; ++j)
                s += colsum[(r + i) * 112 + c + j];   // c>=110 reads pad garbage -> masked px only
        p_sq[t] = s;
    }
    __syncthreads();

    const int lane  = t & 63;
    const int wave  = t >> 6;            // 4 waves x 32 filters
    const int laneM = lane & 15;
    const int quad  = lane >> 4;

    // A = ccs (M = filters): lane's filter-in-tile = laneM
    const unsigned short* ap0 = ccs_t + (size_t)(wave * 32 + laneM) * KD + quad * 8;
    const unsigned short* ap1 = ap0 + 16 * KD;

    // per-lane 4 consecutive filters (rows of D): f = wave*32 + ft*16 + quad*4 + e
    const int fb = wave * 32 + quad * 4;

    for (int r = 0; r < ORPB; ++r) {
        f32x4 acc[7][2];
        #pragma unroll
        for (int mi = 0; mi < 7; ++mi) {
            acc[mi][0] = (f32x4){0.f, 0.f, 0.f, 0.f};
            acc[mi][1] = (f32x4){0.f, 0.f, 0.f, 0.f};
        }

        #pragma unroll
        for (int kb = 0; kb < 9; ++kb) {     // one k-block per tap (ki,kj), K=32 channels
            const int ki = kb / 3, kj = kb % 3;
            bf16x8 a0 = *(const bf16x8*)(ap0 + kb * 32);
            bf16x8 a1 = *(const bf16x8*)(ap1 + kb * 32);
            #pragma unroll
            for (int mi = 0; mi < 7; ++mi) {
                // B[k = quad*8+j][n = laneM]: pixel px = mi*16+laneM+kj, staged row r+ki
                const bf16x8 bf = *(const bf16x8*)(&xs[((r + ki) * RPX + mi * 16 + laneM + kj) * XP + quad * 8]);
                acc[mi][0] = __builtin_amdgcn_mfma_f32_16x16x32_bf16(a0, bf, acc[mi][0], 0, 0, 0);
                acc[mi][1] = __builtin_amdgcn_mfma_f32_16x16x32_bf16(a1, bf, acc[mi][1], 0, 0, 0);
            }
        }

        // Epilogue: D[row = filter (quad*4+e)][col = pixel (laneM)] -> float4 stores along filters.
        // cs/beta loaded here (L1-hot) to keep live ranges short under the 128-VGPR cap.
        // NON-TEMPORAL: out is write-once, never read; avoids write-allocate RFO + L2/L3 pollution.
        const float4 cs0 = *(const float4*)(c_sq + fb);
        const float4 cs1 = *(const float4*)(c_sq + fb + 16);
        const float4 bt0 = *(const float4*)(beta + fb);
        const float4 bt1 = *(const float4*)(beta + fb + 16);
        float* orow = out + (size_t)((b * HO + y0 + r) * WO) * NF;
        #pragma unroll
        for (int mi = 0; mi < 7; ++mi) {
            const int px = mi * 16 + laneM;
            const float ps = p_sq[r * 112 + px];
            float* op = orow + (size_t)px * NF + fb;
            #pragma unroll
            for (int ft = 0; ft < 2; ++ft) {
                const float4 cs = ft ? cs1 : cs0;
                const float4 bt = ft ? bt1 : bt0;
                f32x4 o;
                o[0] = __expf(-bt.x * (ps - 2.f * acc[mi][ft][0] + cs.x));
                o[1] = __expf(-bt.y * (ps - 2.f * acc[mi][ft][1] + cs.y));
                o[2] = __expf(-bt.z * (ps - 2.f * acc[mi][ft][2] + cs.z));
                o[3] = __expf(-bt.w * (ps - 2.f * acc[mi][ft][3] + cs.w));
                if (px < WO)
                    __builtin_nontemporal_store(o, (f32x4*)(op + ft * 16));
            }
        }
    }
}

extern "C" void kernel_launch(void* const* d_in, const int* in_sizes, int n_in,
                              void* d_out, int out_size, void* d_ws, size_t ws_size,
                              hipStream_t stream) {
    const float* x    = (const float*)d_in[0];
    const float* ccs  = (const float*)d_in[1];
    const float* beta = (const float*)d_in[2];
    float* out = (float*)d_out;

    unsigned short* ccs_t = (unsigned short*)d_ws;                              // 128*288 bf16
    float* c_sq = (float*)((char*)d_ws + 128 * KD * sizeof(unsigned short));    // 128 f32

    rbf_prologue<<<144, 256, 0, stream>>>(ccs, ccs_t, c_sq);
    rbf_main<<<dim3(55, 32), 256, 0, stream>>>(x, ccs_t, c_sq, beta, out);
}

// Round 5
// 262.295 us; speedup vs baseline: 1.2093x; 1.2093x over previous
//
#include <hip/hip_runtime.h>

// RBFolution: out[b,y,x,f] = exp(-beta[f] * (||patch||^2 - 2 patch.ccs[:,f] + ||ccs[:,f]||^2))
// x: [32,112,112,32] f32, ccs: [288,128] f32, beta: [128] f32, out: [32,110,110,128] f32
//
// bf16 MFMA implicit GEMM; p_sq/c_sq fp32-exact (only cross term bf16, err ~1e-5).
// R9 = R8 + FULL-LINE output stores. R8 counters: WRITE=299MB vs 198MB actual (1.51x),
// BW pinned at 3.0 TB/s while fill hits 6.6 -> each 128B out-line was covered by two
// 64B stores from DIFFERENT instructions (ft=0/ft=1), i.e. partial masked bursts.
// A wave already owns complete lines (its 32 filters = bytes [px*512+wave*128,+128),
// spread over 4 lanes x 2 regs): one __shfl_xor(.,1) lane-pair swap lets instr 1 write
// even pixels' FULL lines and instr 2 odd pixels' full lines (8 full 128B lines per
// global_store_dwordx4). Same instruction count; nt kept (write-once output).
// R8/R5 lessons kept: occupancy is NOT the lever (33% both geometries, dur equal);
// VGPR_Count=64 is natural (acc in AGPRs), not a strangle.

typedef __attribute__((ext_vector_type(8))) short bf16x8;
typedef __attribute__((ext_vector_type(4))) float f32x4;

#define HH 112
#define WW 112
#define CC 32
#define HO 110
#define WO 110
#define NF 128
#define KD 288
#define RPX 114        // pixels per staged row in LDS (reads reach px 113)
#define XP 32          // bf16 elems per pixel (64 B): b128 frag reads spread uniformly over banks
#define ORPB 2         // output rows per block
#define SROWS 4        // staged input rows per block

__device__ __forceinline__ unsigned short f32_to_bf16(float f) {
    unsigned u = __float_as_uint(f);
    unsigned r = u + 0x7FFFu + ((u >> 16) & 1u);   // round-to-nearest-even
    return (unsigned short)(r >> 16);
}

// --- Prologue: ccs [288][128] f32 -> ccs_t [128][288] bf16 (all blocks);
//     block 0 threads 0..127 also compute c_sq[f] = sum_d ccs[d][f]^2 (coalesced column walk).
__global__ __launch_bounds__(256) void rbf_prologue(const float* __restrict__ ccs,
                                                    unsigned short* __restrict__ ccs_t,
                                                    float* __restrict__ c_sq) {
    int idx = blockIdx.x * 256 + threadIdx.x;     // 0..36863, coalesced read
    int d = idx >> 7;
    int f = idx & 127;
    ccs_t[f * KD + d] = f32_to_bf16(ccs[idx]);
    if (blockIdx.x == 0 && threadIdx.x < 128) {
        const int fc = threadIdx.x;
        float s = 0.f;
        #pragma unroll 8
        for (int dd = 0; dd < KD; ++dd) {
            float v = ccs[dd * NF + fc];
            s += v * v;
        }
        c_sq[fc] = s;
    }
}

// --- Main: one block per (2-row strip, b). 2 output rows, 4 staged input rows.
__global__ __launch_bounds__(256, 4) void rbf_main(const float* __restrict__ x,
                                                   const unsigned short* __restrict__ ccs_t,
                                                   const float* __restrict__ c_sq,
                                                   const float* __restrict__ beta,
                                                   float* __restrict__ out) {
    __shared__ unsigned short xs[SROWS * RPX * XP];   // 29184 B
    __shared__ float colsum[452];                     // 4 rows x 112 (stride 112) + overrun pad
    __shared__ float p_sq[ORPB * 112];                // 896 B   -> 31.9 KB total

    const int t = threadIdx.x;
    const int y0 = blockIdx.x * ORPB;  // 0,2,...,108
    const int b = blockIdx.y;          // 0..31

    // Stage x[y0..y0+3][0..111][0..31] -> LDS bf16; colsum from fp32 (exact p_sq).
    // 3584 float4 units = 14 * 256 exactly (no tail). y0+3 <= 111 always (no clamp).
    #pragma unroll
    for (int p = 0; p < 14; ++p) {
        int idx = t + p * 256;
        int q = idx & 7;              // channel quarter (4 floats)
        int ic = idx >> 3;            // 0..447 = i*112 + col
        int col = ic % 112;
        int i = ic / 112;
        const float4 v = *(const float4*)(x + ((size_t)(b * HH + y0 + i) * WW + col) * CC + q * 4);
        unsigned short h0 = f32_to_bf16(v.x), h1 = f32_to_bf16(v.y);
        unsigned short h2 = f32_to_bf16(v.z), h3 = f32_to_bf16(v.w);
        uint2 pk;
        pk.x = (unsigned)h0 | ((unsigned)h1 << 16);
        pk.y = (unsigned)h2 | ((unsigned)h3 << 16);
        *(uint2*)(&xs[(i * RPX + col) * XP + q * 4]) = pk;   // 8B, contiguous per wave
        float part = v.x * v.x + v.y * v.y + v.z * v.z + v.w * v.w;
        part += __shfl_xor(part, 1);
        part += __shfl_xor(part, 2);
        part += __shfl_xor(part, 4);
        if (q == 0) colsum[ic] = part;   // stride 112
    }
    __syncthreads();

    if (t < ORPB * 112) {   // 224 threads
        int r = t / 112;
        int c = t - r * 112;
        float s = 0.f;
        #pragma unroll
        for (int i = 0; i < 3; ++i)
            #pragma unroll
            for (int j = 0; j < 3; ++j)
                s += colsum[(r + i) * 112 + c + j];   // c>=110 reads pad garbage -> masked px only
        p_sq[t] = s;
    }
    __syncthreads();

    const int lane  = t & 63;
    const int wave  = t >> 6;            // 4 waves x 32 filters
    const int laneM = lane & 15;
    const int quad  = lane >> 4;
    const int pl    = laneM & 1;         // pair parity (even/odd pixel of the lane pair)

    // A = ccs (M = filters): lane's filter-in-tile = laneM
    const unsigned short* ap0 = ccs_t + (size_t)(wave * 32 + laneM) * KD + quad * 8;
    const unsigned short* ap1 = ap0 + 16 * KD;

    // per-lane 4 consecutive filters (rows of D): f = wave*32 + ft*16 + quad*4 + e
    const int fb = wave * 32 + quad * 4;

    for (int r = 0; r < ORPB; ++r) {
        f32x4 acc[7][2];
        #pragma unroll
        for (int mi = 0; mi < 7; ++mi) {
            acc[mi][0] = (f32x4){0.f, 0.f, 0.f, 0.f};
            acc[mi][1] = (f32x4){0.f, 0.f, 0.f, 0.f};
        }

        #pragma unroll
        for (int kb = 0; kb < 9; ++kb) {     // one k-block per tap (ki,kj), K=32 channels
            const int ki = kb / 3, kj = kb % 3;
            bf16x8 a0 = *(const bf16x8*)(ap0 + kb * 32);
            bf16x8 a1 = *(const bf16x8*)(ap1 + kb * 32);
            #pragma unroll
            for (int mi = 0; mi < 7; ++mi) {
                // B[k = quad*8+j][n = laneM]: pixel px = mi*16+laneM+kj, staged row r+ki
                const bf16x8 bf = *(const bf16x8*)(&xs[((r + ki) * RPX + mi * 16 + laneM + kj) * XP + quad * 8]);
                acc[mi][0] = __builtin_amdgcn_mfma_f32_16x16x32_bf16(a0, bf, acc[mi][0], 0, 0, 0);
                acc[mi][1] = __builtin_amdgcn_mfma_f32_16x16x32_bf16(a1, bf, acc[mi][1], 0, 0, 0);
            }
        }

        // Epilogue: lane holds pixel px = mi*16+laneM, filters {fb..fb+3, fb+16..fb+19}.
        // After exp, lane-pair swap (xor 1) so instr 1 writes EVEN pixels' full 128B lines
        // (8 lanes x 16B contiguous per line) and instr 2 writes ODD pixels' lines.
        const float4 cs0 = *(const float4*)(c_sq + fb);
        const float4 cs1 = *(const float4*)(c_sq + fb + 16);
        const float4 bt0 = *(const float4*)(beta + fb);
        const float4 bt1 = *(const float4*)(beta + fb + 16);
        float* orow = out + (size_t)((b * HO + y0 + r) * WO) * NF;
        #pragma unroll
        for (int mi = 0; mi < 7; ++mi) {
            const int px = mi * 16 + laneM;
            const float ps = p_sq[r * 112 + px];
            f32x4 o0, o1;
            o0[0] = __expf(-bt0.x * (ps - 2.f * acc[mi][0][0] + cs0.x));
            o0[1] = __expf(-bt0.y * (ps - 2.f * acc[mi][0][1] + cs0.y));
            o0[2] = __expf(-bt0.z * (ps - 2.f * acc[mi][0][2] + cs0.z));
            o0[3] = __expf(-bt0.w * (ps - 2.f * acc[mi][0][3] + cs0.w));
            o1[0] = __expf(-bt1.x * (ps - 2.f * acc[mi][1][0] + cs1.x));
            o1[1] = __expf(-bt1.y * (ps - 2.f * acc[mi][1][1] + cs1.y));
            o1[2] = __expf(-bt1.z * (ps - 2.f * acc[mi][1][2] + cs1.z));
            o1[3] = __expf(-bt1.w * (ps - 2.f * acc[mi][1][3] + cs1.w));

            // even lane sends its ft1 half, odd lane sends its ft0 half; partner receives.
            f32x4 sendv = pl ? o0 : o1;
            f32x4 recv;
            recv[0] = __shfl_xor(sendv[0], 1);
            recv[1] = __shfl_xor(sendv[1], 1);
            recv[2] = __shfl_xor(sendv[2], 1);
            recv[3] = __shfl_xor(sendv[3], 1);
            const f32x4 v1 = pl ? recv : o0;   // even-pixel line: even lane ft0, odd lane (even px) ft1
            const f32x4 v2 = pl ? o1 : recv;   // odd-pixel line:  even lane (odd px) ft0, odd lane ft1

            const int pxe = mi * 16 + (laneM & ~1);   // even pixel of the pair
            // line base for even pixel: pxe*NF + wave*32; this lane's 16B slot: + pl*16 + quad*4
            float* op1 = orow + (size_t)pxe * NF + fb + pl * 16;
            if (pxe < WO)
                __builtin_nontemporal_store(v1, (f32x4*)op1);
            if (pxe + 1 < WO)
                __builtin_nontemporal_store(v2, (f32x4*)(op1 + NF));
        }
    }
}

extern "C" void kernel_launch(void* const* d_in, const int* in_sizes, int n_in,
                              void* d_out, int out_size, void* d_ws, size_t ws_size,
                              hipStream_t stream) {
    const float* x    = (const float*)d_in[0];
    const float* ccs  = (const float*)d_in[1];
    const float* beta = (const float*)d_in[2];
    float* out = (float*)d_out;

    unsigned short* ccs_t = (unsigned short*)d_ws;                              // 128*288 bf16
    float* c_sq = (float*)((char*)d_ws + 128 * KD * sizeof(unsigned short));    // 128 f32

    rbf_prologue<<<144, 256, 0, stream>>>(ccs, ccs_t, c_sq);
    rbf_main<<<dim3(55, 32), 256, 0, stream>>>(x, ccs_t, c_sq, beta, out);
}